// Round 6
// baseline (266.931 us; speedup 1.0000x reference)
//
#include <hip/hip_runtime.h>
#include <math.h>

#define BSZ    4
#define NTOK   6400      // 40*160
#define DMODEL 256
#define NHEAD  8
#define HDIM   32
#define NPTS   9
#define HSP    40
#define WSP    160
#define KDIM   256
#define MTOT   (BSZ*NTOK)   // 25600
#define NFUSED 912          // 256 q + 144 off + 512 kv

typedef short  short8  __attribute__((ext_vector_type(8)));
typedef float  floatx4 __attribute__((ext_vector_type(4)));

__device__ __forceinline__ ushort f2bf(float f) {
    uint u = __float_as_uint(f);
    u = (u + 0x7FFFu + ((u >> 16) & 1u)) >> 16;   // RNE
    return (ushort)u;
}

// unpack 8 packed bf16 (uint4) -> 8 fp32, 1 VALU/elem
__device__ __forceinline__ void unpack8(uint4 u, float* f) {
    f[0] = __uint_as_float(u.x << 16); f[1] = __uint_as_float(u.x & 0xFFFF0000u);
    f[2] = __uint_as_float(u.y << 16); f[3] = __uint_as_float(u.y & 0xFFFF0000u);
    f[4] = __uint_as_float(u.z << 16); f[5] = __uint_as_float(u.z & 0xFFFF0000u);
    f[6] = __uint_as_float(u.w << 16); f[7] = __uint_as_float(u.w & 0xFFFF0000u);
}

// ---------------------------------------------------------------------------
// All fp32->bf16 casts in one launch. Block = 1024 elems.
// x 6400 | Wq 64 | Woff 36 | Wkv 128 | Wout 64 => 6692 blocks.
// Wq/Woff/Wkv write contiguously -> fused (912,256) weight matrix.
// ---------------------------------------------------------------------------
__global__ __launch_bounds__(256) void cast_all(
    const float* __restrict__ x,   const float* __restrict__ Wq,
    const float* __restrict__ Woff,const float* __restrict__ Wkv,
    const float* __restrict__ Wout,
    ushort* __restrict__ xb, ushort* __restrict__ wfused, ushort* __restrict__ woutb)
{
    const int bid = blockIdx.x;
    const float* src; ushort* dst; int base;
    if      (bid < 6400) { src = x;    dst = xb;              base = bid; }
    else if (bid < 6464) { src = Wq;   dst = wfused;          base = bid - 6400; }
    else if (bid < 6500) { src = Woff; dst = wfused + 65536;  base = bid - 6464; }
    else if (bid < 6628) { src = Wkv;  dst = wfused + 102400; base = bid - 6500; }
    else                 { src = Wout; dst = woutb;           base = bid - 6628; }
    const int i = base * 1024 + threadIdx.x * 4;
    float4 v = *(const float4*)(src + i);
    ushort4 o;
    o.x = f2bf(v.x); o.y = f2bf(v.y); o.z = f2bf(v.z); o.w = f2bf(v.w);
    *(ushort4*)(dst + i) = o;
}

// ---------------------------------------------------------------------------
// Fused input GEMM, barrier-free K-loop WITH register-double-buffered A
// prefetch (the R5 structure + pipelining).
// Block: 256 rows x 128 cols, 4 waves, wave = 64 rows x 128 cols (acc 4x8).
// B tile (128 cols x 256 K = 64 KB) staged to LDS once, XOR-swizzled; only
// ONE barrier in the kernel -> A loads stay in flight across MFMAs
// (fine-grained vmcnt, never a forced drain).
// Epilogue by column: [0,256) q bf16 | [256,400) tanh*4 fp32 |
// [400,912) k/v scatter bf16 (B*H,N,32) | >=912 dead.
// ---------------------------------------------------------------------------
__global__ __launch_bounds__(256, 2) void gemm_fused(
    const ushort* __restrict__ Xb,
    const ushort* __restrict__ Wb,
    const float* __restrict__ bq, const float* __restrict__ boff,
    const float* __restrict__ bkv,
    ushort* __restrict__ qb, float* __restrict__ off,
    ushort* __restrict__ kfb, ushort* __restrict__ vfb)
{
    __shared__ ushort Bs[128 * 256];   // 64 KB

    const int tid = threadIdx.x;
    const int block_n = blockIdx.x * 128;   // col block (0..7)
    const int block_m = blockIdx.y * 256;   // row block (0..99)
    const int wave = tid >> 6, lane = tid & 63;
    const int l15 = lane & 15, quad = lane >> 4;
    const int wrow = block_m + wave * 64;
    const int sw = l15 & 7;                 // read-side swizzle key

    // ---- stage B once: 128 cols x 32 chunks(16B) ----
    #pragma unroll
    for (int i = 0; i < 16; ++i) {
        const int c = tid + 256 * i;
        const int col = c >> 5, s = c & 31;
        const int gcol = min(block_n + col, NFUSED - 1);
        const uint4 v = *(const uint4*)(Wb + (size_t)gcol * KDIM + s * 8);
        *(uint4*)&Bs[col * 256 + ((s ^ (col & 7)) << 3)] = v;
    }
    __syncthreads();   // the only barrier

    floatx4 acc[4][8];
    #pragma unroll
    for (int i = 0; i < 4; ++i)
        #pragma unroll
        for (int j = 0; j < 8; ++j) {
            acc[i][j][0] = 0.f; acc[i][j][1] = 0.f;
            acc[i][j][2] = 0.f; acc[i][j][3] = 0.f;
        }

    const ushort* Abase = Xb + (size_t)wrow * KDIM + quad * 8;

    // register double-buffered A fragments
    short8 a0[4], a1[4];
    #pragma unroll
    for (int fm = 0; fm < 4; ++fm)
        a0[fm] = *(const short8*)(Abase + (size_t)(fm * 16 + l15) * KDIM);

    #pragma unroll
    for (int k8 = 0; k8 < 8; ++k8) {
        short8* cur = (k8 & 1) ? a1 : a0;
        short8* nxt = (k8 & 1) ? a0 : a1;
        if (k8 < 7) {
            #pragma unroll
            for (int fm = 0; fm < 4; ++fm)
                nxt[fm] = *(const short8*)
                    (Abase + (size_t)(fm * 16 + l15) * KDIM + (k8 + 1) * 32);
        }
        #pragma unroll
        for (int fn = 0; fn < 8; ++fn) {
            const short8 bf = *(const short8*)
                &Bs[(fn * 16 + l15) * 256 + (((k8 * 4 + quad) ^ sw) << 3)];
            #pragma unroll
            for (int fm = 0; fm < 4; ++fm)
                acc[fm][fn] = __builtin_amdgcn_mfma_f32_16x16x32_bf16(
                    cur[fm], bf, acc[fm][fn], 0, 0, 0);
        }
    }

    // ---- epilogue (C/D: col=lane&15, row=quad*4+reg); fn innermost so
    //      stores to the same 64B line issue back-to-back ----
    float bcol[8]; int colv[8];
    #pragma unroll
    for (int fn = 0; fn < 8; ++fn) {
        const int col = block_n + fn * 16 + l15;
        colv[fn] = col;
        bcol[fn] = (col < 256) ? bq[col]
                 : (col < 400) ? boff[col - 256]
                 : (col < NFUSED) ? bkv[col - 400] : 0.f;
    }
    #pragma unroll
    for (int fm = 0; fm < 4; ++fm) {
        #pragma unroll
        for (int r = 0; r < 4; ++r) {
            const int row = wrow + fm * 16 + quad * 4 + r;
            const int b = row / NTOK, n = row % NTOK;
            #pragma unroll
            for (int fn = 0; fn < 8; ++fn) {
                const int col = colv[fn];
                if (col >= NFUSED) continue;
                const float val = acc[fm][fn][r] + bcol[fn];
                if (col < 256) {
                    qb[(size_t)row * DMODEL + col] = f2bf(val);
                } else if (col < 400) {
                    off[(size_t)row * 144 + (col - 256)] = tanhf(val) * 4.0f;
                } else {
                    const int kc = col - 400;            // 0..511
                    const int hh = (kc >> 5) & 7, c = kc & 31;
                    const size_t o = (((size_t)(b * NHEAD + hh)) * NTOK + n) * HDIM + c;
                    if (kc < 256) kfb[o] = f2bf(val);
                    else          vfb[o] = f2bf(val);
                }
            }
        }
    }
}

// ---------------------------------------------------------------------------
// Final GEMM: out = attnb @ Wout^T + bout (fp32). Same pipelined barrier-free
// structure. Block: 256 rows x 64 cols (4 waves x 64x64, acc 4x4);
// B tile 64x256 = 32 KB LDS. Grid (4,100) = 400 blocks.
// ---------------------------------------------------------------------------
__global__ __launch_bounds__(256, 3) void gemm_out(
    const ushort* __restrict__ Xb,
    const ushort* __restrict__ Wb,
    const float* __restrict__ bias,
    float* __restrict__ Y)
{
    __shared__ ushort Bs[64 * 256];    // 32 KB

    const int tid = threadIdx.x;
    const int block_n = blockIdx.x * 64;
    const int block_m = blockIdx.y * 256;
    const int wave = tid >> 6, lane = tid & 63;
    const int l15 = lane & 15, quad = lane >> 4;
    const int wrow = block_m + wave * 64;
    const int sw = l15 & 7;

    #pragma unroll
    for (int i = 0; i < 8; ++i) {
        const int c = tid + 256 * i;          // 64 cols x 32 chunks
        const int col = c >> 5, s = c & 31;
        const uint4 v = *(const uint4*)(Wb + (size_t)(block_n + col) * KDIM + s * 8);
        *(uint4*)&Bs[col * 256 + ((s ^ (col & 7)) << 3)] = v;
    }
    __syncthreads();

    floatx4 acc[4][4];
    #pragma unroll
    for (int i = 0; i < 4; ++i)
        #pragma unroll
        for (int j = 0; j < 4; ++j) {
            acc[i][j][0] = 0.f; acc[i][j][1] = 0.f;
            acc[i][j][2] = 0.f; acc[i][j][3] = 0.f;
        }

    const ushort* Abase = Xb + (size_t)wrow * KDIM + quad * 8;

    short8 a0[4], a1[4];
    #pragma unroll
    for (int fm = 0; fm < 4; ++fm)
        a0[fm] = *(const short8*)(Abase + (size_t)(fm * 16 + l15) * KDIM);

    #pragma unroll
    for (int k8 = 0; k8 < 8; ++k8) {
        short8* cur = (k8 & 1) ? a1 : a0;
        short8* nxt = (k8 & 1) ? a0 : a1;
        if (k8 < 7) {
            #pragma unroll
            for (int fm = 0; fm < 4; ++fm)
                nxt[fm] = *(const short8*)
                    (Abase + (size_t)(fm * 16 + l15) * KDIM + (k8 + 1) * 32);
        }
        #pragma unroll
        for (int fn = 0; fn < 4; ++fn) {
            const short8 bf = *(const short8*)
                &Bs[(fn * 16 + l15) * 256 + (((k8 * 4 + quad) ^ sw) << 3)];
            #pragma unroll
            for (int fm = 0; fm < 4; ++fm)
                acc[fm][fn] = __builtin_amdgcn_mfma_f32_16x16x32_bf16(
                    cur[fm], bf, acc[fm][fn], 0, 0, 0);
        }
    }

    #pragma unroll
    for (int fm = 0; fm < 4; ++fm) {
        #pragma unroll
        for (int r = 0; r < 4; ++r) {
            const int row = wrow + fm * 16 + quad * 4 + r;
            #pragma unroll
            for (int fn = 0; fn < 4; ++fn) {
                const int col = block_n + fn * 16 + l15;
                Y[(size_t)row * DMODEL + col] = acc[fm][fn][r] + bias[col];
            }
        }
    }
}

// ---------------------------------------------------------------------------
// Deformable sampling + online-softmax attention (R3-measured version:
// separate k/v buffers, 68 µs). Wave = 2 tokens x 8 heads x 4 lanes; each
// lane owns 8 channels (16B loads). bf16 q/k/v in, fp32 math, bf16 out.
// ---------------------------------------------------------------------------
__global__ __launch_bounds__(256) void deform_attn(
    const ushort* __restrict__ qb,    // (M,256) bf16
    const float* __restrict__ off,    // (M,144) fp32 (tanh*4 applied)
    const ushort* __restrict__ kfb,   // (B*H,N,32) bf16
    const ushort* __restrict__ vfb,
    ushort* __restrict__ attnb)       // (M,256) bf16
{
    const int lane = threadIdx.x & 63;
    const int token = blockIdx.x * 8 + (threadIdx.x >> 6) * 2 + (lane >> 5);
    const int h = (lane >> 2) & 7, lc = lane & 3;
    const int b = token / NTOK, n = token % NTOK;

    const uint4 qu = *(const uint4*)(qb + (size_t)token * DMODEL + h * HDIM + lc * 8);
    float q[8]; unpack8(qu, q);

    const float* ob = off + (size_t)token * 144 + h * (NPTS * 2);
    float2 offs[NPTS];
    #pragma unroll
    for (int p = 0; p < NPTS; ++p) offs[p] = *(const float2*)(ob + 2 * p);

    const float bx = (float)(n % WSP), by = (float)(n / WSP);
    const ushort* kb = kfb + (size_t)(b * NHEAD + h) * NTOK * HDIM + lc * 8;
    const ushort* vb = vfb + (size_t)(b * NHEAD + h) * NTOK * HDIM + lc * 8;

    float m = -INFINITY, s = 0.f;
    float o[8];
    #pragma unroll
    for (int c = 0; c < 8; ++c) o[c] = 0.f;

    #pragma unroll
    for (int p = 0; p < NPTS; ++p) {
        const float sx = bx + offs[p].x, sy = by + offs[p].y;
        const float fx0 = floorf(sx), fy0 = floorf(sy);
        const float wx1 = sx - fx0, wx0 = 1.0f - wx1;
        const float wy1 = sy - fy0, wy0 = 1.0f - wy1;
        const int ix0 = (int)fx0, iy0 = (int)fy0;
        const int ix1 = ix0 + 1, iy1 = iy0 + 1;
        const bool vx0 = (ix0 >= 0) & (ix0 <= WSP - 1);
        const bool vx1 = (ix1 >= 0) & (ix1 <= WSP - 1);
        const bool vy0 = (iy0 >= 0) & (iy0 <= HSP - 1);
        const bool vy1 = (iy1 >= 0) & (iy1 <= HSP - 1);
        const int cx0 = min(max(ix0, 0), WSP - 1);
        const int cx1 = min(max(ix1, 0), WSP - 1);
        const int cy0 = min(max(iy0, 0), HSP - 1);
        const int cy1 = min(max(iy1, 0), HSP - 1);
        const float w00 = wx0 * wy0 * (float)(vx0 && vy0);
        const float w10 = wx1 * wy0 * (float)(vx1 && vy0);
        const float w01 = wx0 * wy1 * (float)(vx0 && vy1);
        const float w11 = wx1 * wy1 * (float)(vx1 && vy1);
        const int i00 = (cy0 * WSP + cx0) * HDIM;
        const int i10 = (cy0 * WSP + cx1) * HDIM;
        const int i01 = (cy1 * WSP + cx0) * HDIM;
        const int i11 = (cy1 * WSP + cx1) * HDIM;

        const uint4 ku0 = *(const uint4*)(kb + i00);
        const uint4 ku1 = *(const uint4*)(kb + i10);
        const uint4 ku2 = *(const uint4*)(kb + i01);
        const uint4 ku3 = *(const uint4*)(kb + i11);
        const uint4 vu0 = *(const uint4*)(vb + i00);
        const uint4 vu1 = *(const uint4*)(vb + i10);
        const uint4 vu2 = *(const uint4*)(vb + i01);
        const uint4 vu3 = *(const uint4*)(vb + i11);

        float kc[8], d00 = 0.f, d10 = 0.f, d01 = 0.f, d11 = 0.f;
        unpack8(ku0, kc);
        #pragma unroll
        for (int c = 0; c < 8; ++c) d00 = fmaf(q[c], kc[c], d00);
        unpack8(ku1, kc);
        #pragma unroll
        for (int c = 0; c < 8; ++c) d10 = fmaf(q[c], kc[c], d10);
        unpack8(ku2, kc);
        #pragma unroll
        for (int c = 0; c < 8; ++c) d01 = fmaf(q[c], kc[c], d01);
        unpack8(ku3, kc);
        #pragma unroll
        for (int c = 0; c < 8; ++c) d11 = fmaf(q[c], kc[c], d11);

        float part = w00 * d00 + w10 * d10 + w01 * d01 + w11 * d11;
        part += __shfl_xor(part, 1, 64);
        part += __shfl_xor(part, 2, 64);
        const float l = part * 0.17677669529663687f;   // 32^-0.5

        const float m1 = fmaxf(m, l);
        const float corr = __expf(m - m1);
        const float e = __expf(l - m1);
        s = fmaf(s, corr, e);
        m = m1;

        const float e00 = e * w00, e10 = e * w10, e01 = e * w01, e11 = e * w11;
        float v0[8], v1[8], v2[8], v3[8];
        unpack8(vu0, v0); unpack8(vu1, v1); unpack8(vu2, v2); unpack8(vu3, v3);
        #pragma unroll
        for (int c = 0; c < 8; ++c)
            o[c] = fmaf(o[c], corr,
                        fmaf(e00, v0[c], fmaf(e10, v1[c], fmaf(e01, v2[c], e11 * v3[c]))));
    }

    const float inv = 1.0f / s;
    uint4 ru;
    ru.x = (uint)f2bf(o[0] * inv) | ((uint)f2bf(o[1] * inv) << 16);
    ru.y = (uint)f2bf(o[2] * inv) | ((uint)f2bf(o[3] * inv) << 16);
    ru.z = (uint)f2bf(o[4] * inv) | ((uint)f2bf(o[5] * inv) << 16);
    ru.w = (uint)f2bf(o[6] * inv) | ((uint)f2bf(o[7] * inv) << 16);
    *(uint4*)(attnb + (size_t)token * DMODEL + h * HDIM + lc * 8) = ru;
}

// ---------------------------------------------------------------------------
extern "C" void kernel_launch(void* const* d_in, const int* in_sizes, int n_in,
                              void* d_out, int out_size, void* d_ws, size_t ws_size,
                              hipStream_t stream) {
    const float* x    = (const float*)d_in[0];
    const float* Wq   = (const float*)d_in[1];
    const float* bq   = (const float*)d_in[2];
    const float* Woff = (const float*)d_in[3];
    const float* boff = (const float*)d_in[4];
    const float* Wkv  = (const float*)d_in[5];
    const float* bkv  = (const float*)d_in[6];
    const float* Wout = (const float*)d_in[7];
    const float* bout = (const float*)d_in[8];

    // workspace layout (~68 MB)
    ushort* xb     = (ushort*)d_ws;                          // 6,553,600 (reused as attnb)
    ushort* qb     = xb + (size_t)MTOT * DMODEL;             // 6,553,600
    float*  off    = (float*)(qb + (size_t)MTOT * DMODEL);   // 3,686,400 fp32
    ushort* kfb    = (ushort*)(off + (size_t)MTOT * 144);    // 6,553,600
    ushort* vfb    = kfb + (size_t)MTOT * DMODEL;            // 6,553,600
    ushort* wfused = vfb + (size_t)MTOT * DMODEL;            // 233,472 (Wq|Woff|Wkv)
    ushort* woutb  = wfused + NFUSED * KDIM;                 // 65,536
    ushort* attnb  = xb;   // xb dead after gemm_fused

    cast_all<<<dim3(6692), dim3(256), 0, stream>>>(x, Wq, Woff, Wkv, Wout,
                                                   xb, wfused, woutb);
    gemm_fused<<<dim3(8, 100), dim3(256), 0, stream>>>(xb, wfused, bq, boff, bkv,
                                                       qb, off, kfb, vfb);
    deform_attn<<<dim3(3200), dim3(256), 0, stream>>>(qb, off, kfb, vfb, attnb);
    gemm_out<<<dim3(4, 100), dim3(256), 0, stream>>>(attnb, woutb, bout, (float*)d_out);
}

// Round 7
// 218.122 us; speedup vs baseline: 1.2238x; 1.2238x over previous
//
#include <hip/hip_runtime.h>
#include <math.h>

#define BSZ    4
#define NTOK   6400      // 40*160
#define DMODEL 256
#define NHEAD  8
#define HDIM   32
#define NPTS   9
#define HSP    40
#define WSP    160
#define KDIM   256
#define MTOT   (BSZ*NTOK)   // 25600
#define NFUSED 912          // 256 q + 144 off + 512 kv

typedef short  short8  __attribute__((ext_vector_type(8)));
typedef float  floatx4 __attribute__((ext_vector_type(4)));

__device__ __forceinline__ ushort f2bf(float f) {
    uint u = __float_as_uint(f);
    u = (u + 0x7FFFu + ((u >> 16) & 1u)) >> 16;   // RNE
    return (ushort)u;
}

// branch-free fast tanh: 1 - 2/(e^2x + 1); exact at +-inf, ~1e-6 rel err
__device__ __forceinline__ float fast_tanh(float v) {
    const float e = __expf(2.0f * v);
    return 1.0f - 2.0f / (e + 1.0f);
}

// unpack 8 packed bf16 (uint4) -> 8 fp32, 1 VALU/elem
__device__ __forceinline__ void unpack8(uint4 u, float* f) {
    f[0] = __uint_as_float(u.x << 16); f[1] = __uint_as_float(u.x & 0xFFFF0000u);
    f[2] = __uint_as_float(u.y << 16); f[3] = __uint_as_float(u.y & 0xFFFF0000u);
    f[4] = __uint_as_float(u.z << 16); f[5] = __uint_as_float(u.z & 0xFFFF0000u);
    f[6] = __uint_as_float(u.w << 16); f[7] = __uint_as_float(u.w & 0xFFFF0000u);
}

// ---------------------------------------------------------------------------
// All fp32->bf16 casts in one launch. Block = 1024 elems.
// x 6400 | Wq 64 | Woff 36 | Wkv 128 | Wout 64 => 6692 blocks.
// ---------------------------------------------------------------------------
__global__ __launch_bounds__(256) void cast_all(
    const float* __restrict__ x,   const float* __restrict__ Wq,
    const float* __restrict__ Woff,const float* __restrict__ Wkv,
    const float* __restrict__ Wout,
    ushort* __restrict__ xb, ushort* __restrict__ wfused, ushort* __restrict__ woutb)
{
    const int bid = blockIdx.x;
    const float* src; ushort* dst; int base;
    if      (bid < 6400) { src = x;    dst = xb;              base = bid; }
    else if (bid < 6464) { src = Wq;   dst = wfused;          base = bid - 6400; }
    else if (bid < 6500) { src = Woff; dst = wfused + 65536;  base = bid - 6464; }
    else if (bid < 6628) { src = Wkv;  dst = wfused + 102400; base = bid - 6500; }
    else                 { src = Wout; dst = woutb;           base = bid - 6628; }
    const int i = base * 1024 + threadIdx.x * 4;
    float4 v = *(const float4*)(src + i);
    ushort4 o;
    o.x = f2bf(v.x); o.y = f2bf(v.y); o.z = f2bf(v.z); o.w = f2bf(v.w);
    *(ushort4*)(dst + i) = o;
}

// ---------------------------------------------------------------------------
// bf16 MFMA GEMM, 128x128 tile, 2-LDS-buffer reg-staged pipeline:
//   barrier -> issue global loads(k+1) -> compute MFMAs on buf[k&1]
//           -> ds_write buf[(k+1)&1]   (vmcnt wait lands AFTER compute)
// Exactly one __syncthreads per iter; vmcnt is naturally 0 at the barrier.
// XOR chunk swizzle (phys = q ^ ((row^(row>>2))&3)) -> 2-way (free) banks on
// both the ds_write and the fragment ds_read.
// MODE 0 (fused, Ncols=912): [0,256) q bf16 | [256,400) fast_tanh*4 fp32 |
//                            [400,912) k/v scatter bf16 (B*H,N,32)
// MODE 1 (out,  Ncols=256): fp32 store Y = acc + bias
// ---------------------------------------------------------------------------
template <int MODE>
__global__ __launch_bounds__(256, 3) void gemm_mfma(
    const ushort* __restrict__ Xb,
    const ushort* __restrict__ Wb,
    const float* __restrict__ bq, const float* __restrict__ boff,
    const float* __restrict__ bkv,
    ushort* __restrict__ qb, float* __restrict__ off,
    ushort* __restrict__ kfb, ushort* __restrict__ vfb,
    float* __restrict__ Y)
{
    const int Ncols = (MODE == 0) ? NFUSED : DMODEL;
    __shared__ ushort As[2][128 * 32];   // 8 KB each
    __shared__ ushort Bs[2][128 * 32];

    const int tid = threadIdx.x;
    const int block_n = blockIdx.x * 128;
    const int block_m = blockIdx.y * 128;
    const int wave = tid >> 6, lane = tid & 63;
    const int wm = (wave >> 1) * 64, wn = (wave & 1) * 64;
    const int l15 = lane & 15, quad = lane >> 4;

    // ---- staging map: thread t owns 16B chunks c = {t, t+256} of the
    //      512-chunk (128 rows x 4 chunks) tile; row = c>>2, q = c&3 ----
    const int r0 = tid >> 2,        q0 = tid & 3;
    const int r1 = (tid + 256) >> 2;                 // rows 64..127, same q0
    const int sw0 = ((r0 ^ (r0 >> 2)) & 3);
    const int sw1 = ((r1 ^ (r1 >> 2)) & 3);
    const int lA0 = r0 * 32 + ((q0 ^ sw0) << 3);
    const int lA1 = r1 * 32 + ((q0 ^ sw1) << 3);

    const ushort* gA0 = Xb + (size_t)(block_m + r0) * KDIM + q0 * 8;
    const ushort* gA1 = Xb + (size_t)(block_m + r1) * KDIM + q0 * 8;
    const int bc0 = min(block_n + r0, Ncols - 1);
    const int bc1 = min(block_n + r1, Ncols - 1);
    const ushort* gB0 = Wb + (size_t)bc0 * KDIM + q0 * 8;
    const ushort* gB1 = Wb + (size_t)bc1 * KDIM + q0 * 8;

    // fragment-read swizzle (independent of fm/fn since wm,wn are mult of 64)
    const int swf = (l15 & 3) ^ ((l15 >> 2) & 3);
    const int physoff = ((quad ^ swf) << 3);

    floatx4 acc[4][4];
    #pragma unroll
    for (int i = 0; i < 4; ++i)
        #pragma unroll
        for (int j = 0; j < 4; ++j) {
            acc[i][j][0] = 0.f; acc[i][j][1] = 0.f;
            acc[i][j][2] = 0.f; acc[i][j][3] = 0.f;
        }

    // ---- prologue: stage tile 0 ----
    {
        uint4 a0 = *(const uint4*)gA0;
        uint4 a1 = *(const uint4*)gA1;
        uint4 b0 = *(const uint4*)gB0;
        uint4 b1 = *(const uint4*)gB1;
        *(uint4*)&As[0][lA0] = a0;  *(uint4*)&As[0][lA1] = a1;
        *(uint4*)&Bs[0][lA0] = b0;  *(uint4*)&Bs[0][lA1] = b1;
    }

    uint4 ra0, ra1, rb0, rb1;
    #pragma unroll
    for (int k8 = 0; k8 < 8; ++k8) {
        __syncthreads();               // vmcnt already 0 here (loads consumed)
        if (k8 < 7) {                  // issue next tile's loads: in flight
            const int ko = (k8 + 1) * 32;      // across the whole compute phase
            ra0 = *(const uint4*)(gA0 + ko);
            ra1 = *(const uint4*)(gA1 + ko);
            rb0 = *(const uint4*)(gB0 + ko);
            rb1 = *(const uint4*)(gB1 + ko);
        }
        const ushort* Ab = As[k8 & 1];
        const ushort* Bb = Bs[k8 & 1];
        short8 af[4], bfr[4];
        #pragma unroll
        for (int f = 0; f < 4; ++f) {
            af[f]  = *(const short8*)&Ab[(wm + f * 16 + l15) * 32 + physoff];
            bfr[f] = *(const short8*)&Bb[(wn + f * 16 + l15) * 32 + physoff];
        }
        #pragma unroll
        for (int fm = 0; fm < 4; ++fm)
            #pragma unroll
            for (int fn = 0; fn < 4; ++fn)
                acc[fm][fn] = __builtin_amdgcn_mfma_f32_16x16x32_bf16(
                    af[fm], bfr[fn], acc[fm][fn], 0, 0, 0);
        if (k8 < 7) {                  // ds_write waits the loads AFTER compute
            ushort* An = As[(k8 + 1) & 1];
            ushort* Bn = Bs[(k8 + 1) & 1];
            *(uint4*)&An[lA0] = ra0;  *(uint4*)&An[lA1] = ra1;
            *(uint4*)&Bn[lA0] = rb0;  *(uint4*)&Bn[lA1] = rb1;
        }
    }

    // ---- epilogue (C/D: col=lane&15, row=quad*4+reg) ----
    float bcol[4]; int colv[4];
    #pragma unroll
    for (int fn = 0; fn < 4; ++fn) {
        const int col = block_n + wn + fn * 16 + l15;
        colv[fn] = col;
        if (MODE == 0) {
            bcol[fn] = (col < 256) ? bq[col]
                     : (col < 400) ? boff[col - 256]
                     : (col < NFUSED) ? bkv[col - 400] : 0.f;
        } else {
            bcol[fn] = bq[col];   // bq carries bout in MODE 1
        }
    }
    #pragma unroll
    for (int fm = 0; fm < 4; ++fm) {
        #pragma unroll
        for (int r = 0; r < 4; ++r) {
            const int row = block_m + wm + fm * 16 + quad * 4 + r;
            const int b = row / NTOK, n = row % NTOK;
            #pragma unroll
            for (int fn = 0; fn < 4; ++fn) {
                const int col = colv[fn];
                const float val = acc[fm][fn][r] + bcol[fn];
                if (MODE == 1) {
                    Y[(size_t)row * DMODEL + col] = val;
                } else {
                    if (col >= NFUSED) continue;
                    if (col < 256) {
                        qb[(size_t)row * DMODEL + col] = f2bf(val);
                    } else if (col < 400) {
                        off[(size_t)row * 144 + (col - 256)] = fast_tanh(val) * 4.0f;
                    } else {
                        const int kc = col - 400;            // 0..511
                        const int hh = (kc >> 5) & 7, c = kc & 31;
                        const size_t o = (((size_t)(b * NHEAD + hh)) * NTOK + n) * HDIM + c;
                        if (kc < 256) kfb[o] = f2bf(val);
                        else          vfb[o] = f2bf(val);
                    }
                }
            }
        }
    }
}

// ---------------------------------------------------------------------------
// Deformable sampling + online-softmax attention (R3-measured version, 68 us;
// byte-identical). Wave = 2 tokens x 8 heads x 4 lanes; each lane owns 8
// channels (16B loads). bf16 q/k/v in, fp32 math, bf16 out.
// ---------------------------------------------------------------------------
__global__ __launch_bounds__(256) void deform_attn(
    const ushort* __restrict__ qb,    // (M,256) bf16
    const float* __restrict__ off,    // (M,144) fp32 (tanh*4 applied)
    const ushort* __restrict__ kfb,   // (B*H,N,32) bf16
    const ushort* __restrict__ vfb,
    ushort* __restrict__ attnb)       // (M,256) bf16
{
    const int lane = threadIdx.x & 63;
    const int token = blockIdx.x * 8 + (threadIdx.x >> 6) * 2 + (lane >> 5);
    const int h = (lane >> 2) & 7, lc = lane & 3;
    const int b = token / NTOK, n = token % NTOK;

    const uint4 qu = *(const uint4*)(qb + (size_t)token * DMODEL + h * HDIM + lc * 8);
    float q[8]; unpack8(qu, q);

    const float* ob = off + (size_t)token * 144 + h * (NPTS * 2);
    float2 offs[NPTS];
    #pragma unroll
    for (int p = 0; p < NPTS; ++p) offs[p] = *(const float2*)(ob + 2 * p);

    const float bx = (float)(n % WSP), by = (float)(n / WSP);
    const ushort* kb = kfb + (size_t)(b * NHEAD + h) * NTOK * HDIM + lc * 8;
    const ushort* vb = vfb + (size_t)(b * NHEAD + h) * NTOK * HDIM + lc * 8;

    float m = -INFINITY, s = 0.f;
    float o[8];
    #pragma unroll
    for (int c = 0; c < 8; ++c) o[c] = 0.f;

    #pragma unroll
    for (int p = 0; p < NPTS; ++p) {
        const float sx = bx + offs[p].x, sy = by + offs[p].y;
        const float fx0 = floorf(sx), fy0 = floorf(sy);
        const float wx1 = sx - fx0, wx0 = 1.0f - wx1;
        const float wy1 = sy - fy0, wy0 = 1.0f - wy1;
        const int ix0 = (int)fx0, iy0 = (int)fy0;
        const int ix1 = ix0 + 1, iy1 = iy0 + 1;
        const bool vx0 = (ix0 >= 0) & (ix0 <= WSP - 1);
        const bool vx1 = (ix1 >= 0) & (ix1 <= WSP - 1);
        const bool vy0 = (iy0 >= 0) & (iy0 <= HSP - 1);
        const bool vy1 = (iy1 >= 0) & (iy1 <= HSP - 1);
        const int cx0 = min(max(ix0, 0), WSP - 1);
        const int cx1 = min(max(ix1, 0), WSP - 1);
        const int cy0 = min(max(iy0, 0), HSP - 1);
        const int cy1 = min(max(iy1, 0), HSP - 1);
        const float w00 = wx0 * wy0 * (float)(vx0 && vy0);
        const float w10 = wx1 * wy0 * (float)(vx1 && vy0);
        const float w01 = wx0 * wy1 * (float)(vx0 && vy1);
        const float w11 = wx1 * wy1 * (float)(vx1 && vy1);
        const int i00 = (cy0 * WSP + cx0) * HDIM;
        const int i10 = (cy0 * WSP + cx1) * HDIM;
        const int i01 = (cy1 * WSP + cx0) * HDIM;
        const int i11 = (cy1 * WSP + cx1) * HDIM;

        const uint4 ku0 = *(const uint4*)(kb + i00);
        const uint4 ku1 = *(const uint4*)(kb + i10);
        const uint4 ku2 = *(const uint4*)(kb + i01);
        const uint4 ku3 = *(const uint4*)(kb + i11);
        const uint4 vu0 = *(const uint4*)(vb + i00);
        const uint4 vu1 = *(const uint4*)(vb + i10);
        const uint4 vu2 = *(const uint4*)(vb + i01);
        const uint4 vu3 = *(const uint4*)(vb + i11);

        float kc[8], d00 = 0.f, d10 = 0.f, d01 = 0.f, d11 = 0.f;
        unpack8(ku0, kc);
        #pragma unroll
        for (int c = 0; c < 8; ++c) d00 = fmaf(q[c], kc[c], d00);
        unpack8(ku1, kc);
        #pragma unroll
        for (int c = 0; c < 8; ++c) d10 = fmaf(q[c], kc[c], d10);
        unpack8(ku2, kc);
        #pragma unroll
        for (int c = 0; c < 8; ++c) d01 = fmaf(q[c], kc[c], d01);
        unpack8(ku3, kc);
        #pragma unroll
        for (int c = 0; c < 8; ++c) d11 = fmaf(q[c], kc[c], d11);

        float part = w00 * d00 + w10 * d10 + w01 * d01 + w11 * d11;
        part += __shfl_xor(part, 1, 64);
        part += __shfl_xor(part, 2, 64);
        const float l = part * 0.17677669529663687f;   // 32^-0.5

        const float m1 = fmaxf(m, l);
        const float corr = __expf(m - m1);
        const float e = __expf(l - m1);
        s = fmaf(s, corr, e);
        m = m1;

        const float e00 = e * w00, e10 = e * w10, e01 = e * w01, e11 = e * w11;
        float v0[8], v1[8], v2[8], v3[8];
        unpack8(vu0, v0); unpack8(vu1, v1); unpack8(vu2, v2); unpack8(vu3, v3);
        #pragma unroll
        for (int c = 0; c < 8; ++c)
            o[c] = fmaf(o[c], corr,
                        fmaf(e00, v0[c], fmaf(e10, v1[c], fmaf(e01, v2[c], e11 * v3[c]))));
    }

    const float inv = 1.0f / s;
    uint4 ru;
    ru.x = (uint)f2bf(o[0] * inv) | ((uint)f2bf(o[1] * inv) << 16);
    ru.y = (uint)f2bf(o[2] * inv) | ((uint)f2bf(o[3] * inv) << 16);
    ru.z = (uint)f2bf(o[4] * inv) | ((uint)f2bf(o[5] * inv) << 16);
    ru.w = (uint)f2bf(o[6] * inv) | ((uint)f2bf(o[7] * inv) << 16);
    *(uint4*)(attnb + (size_t)token * DMODEL + h * HDIM + lc * 8) = ru;
}

// ---------------------------------------------------------------------------
extern "C" void kernel_launch(void* const* d_in, const int* in_sizes, int n_in,
                              void* d_out, int out_size, void* d_ws, size_t ws_size,
                              hipStream_t stream) {
    const float* x    = (const float*)d_in[0];
    const float* Wq   = (const float*)d_in[1];
    const float* bq   = (const float*)d_in[2];
    const float* Woff = (const float*)d_in[3];
    const float* boff = (const float*)d_in[4];
    const float* Wkv  = (const float*)d_in[5];
    const float* bkv  = (const float*)d_in[6];
    const float* Wout = (const float*)d_in[7];
    const float* bout = (const float*)d_in[8];

    // workspace layout (~68 MB)
    ushort* xb     = (ushort*)d_ws;                          // 6,553,600 (reused as attnb)
    ushort* qb     = xb + (size_t)MTOT * DMODEL;             // 6,553,600
    float*  off    = (float*)(qb + (size_t)MTOT * DMODEL);   // 3,686,400 fp32
    ushort* kfb    = (ushort*)(off + (size_t)MTOT * 144);    // 6,553,600
    ushort* vfb    = kfb + (size_t)MTOT * DMODEL;            // 6,553,600
    ushort* wfused = vfb + (size_t)MTOT * DMODEL;            // 233,472 (Wq|Woff|Wkv)
    ushort* woutb  = wfused + NFUSED * KDIM;                 // 65,536
    ushort* attnb  = xb;   // xb dead after gemm_mfma<0>

    cast_all<<<dim3(6692), dim3(256), 0, stream>>>(x, Wq, Woff, Wkv, Wout,
                                                   xb, wfused, woutb);
    gemm_mfma<0><<<dim3(8, 200), dim3(256), 0, stream>>>(
        xb, wfused, bq, boff, bkv, qb, off, kfb, vfb, nullptr);
    deform_attn<<<dim3(3200), dim3(256), 0, stream>>>(qb, off, kfb, vfb, attnb);
    gemm_mfma<1><<<dim3(2, 200), dim3(256), 0, stream>>>(
        attnb, woutb, bout, nullptr, nullptr, nullptr, nullptr, nullptr, nullptr,
        (float*)d_out);
}